// Round 1
// baseline (1039.295 us; speedup 1.0000x reference)
//
#include <hip/hip_runtime.h>

// Problem constants (match reference.py)
#define N_NODES 200000
#define K 16
#define D 8

typedef float vfloat4 __attribute__((ext_vector_type(4)));

// Persistent-wave, software-pipelined version.
//
// One wave owns one node per grid-stride step (node = gw + i*NWAVES).
// Pipeline (2-deep): while computing node i from registers, the wave has
// already issued node i+1's W tiles (4 x dwordx4 = 4 KB), its values
// gather, its bias, and node i+2's neighbor row. No __syncthreads, no LDS:
// the feature broadcast (each feature produced by one lane, consumed by
// two lanes of the SAME wave) is done with ds_bpermute (__shfl).
//
// Lane roles (identical math/order to the verified 1-node-per-wave kernel,
// so numerics are bit-identical):
//   gather: lane l loads values[nbr[n][l>>2]][(l&3)*2 .. +1]
//           -> lane l holds features f = 2l (x) and 2l+1 (y)
//   sweep:  at step t, lane l needs g[32t + (l>>1)]
//           = component ((l>>1)&1) of lane (16t + (l>>2))'s float2
//   W:      lane l at step t holds W[f=32t+(l>>1)][4h..4h+3], h=l&1
//   reduce: xor-butterfly over masks 2..32 (same-parity lanes)
//   store:  lane 0 -> out[n][0..3], lane 1 -> out[n][4..7]

#define NTHREADS 256
#define NBLOCKS  2048                         // 8 blocks/CU * 256 CUs
#define NWAVES   (NBLOCKS * (NTHREADS / 64))  // 8192 waves in flight

__global__ __launch_bounds__(NTHREADS) void node_linear_sigmoid_pipe(
    const float* __restrict__ values,   // [N, D] f32
    const int*   __restrict__ nbr,      // [N, K] int32
    const float* __restrict__ W,        // [N, K*D, D] f32
    const float* __restrict__ bias,     // [N, D] f32
    float*       __restrict__ out)      // [N, D] f32
{
    const int lane = threadIdx.x & 63;
    const int gw   = blockIdx.x * (NTHREADS / 64) + (threadIdx.x >> 6);

    const int  k4  = lane >> 2;               // neighbor slot this lane gathers
    const int  c2  = (lane & 3) * 2;          // float2 column within 8-dim row
    const bool hiC = ((lane >> 1) & 1) != 0;  // broadcast component select

    // Per-stream pointers for this wave/lane; advanced by NWAVES stride/iter.
    const vfloat4* __restrict__ Wp = (const vfloat4*)W + (size_t)gw * 256 + lane;
    const int*     __restrict__ np = nbr + (size_t)gw * K + k4;
    const vfloat4* __restrict__ bp = (const vfloat4*)bias + (size_t)gw * 2 + (lane & 1);
    vfloat4*       __restrict__ op = (vfloat4*)out  + (size_t)gw * 2 + (lane & 1);

    // ---- Prologue: node n = gw ----
    int idxc = *np;                                  // neighbor idx, node n
    vfloat4 w0 = __builtin_nontemporal_load(Wp);         // W tiles, node n
    vfloat4 w1 = __builtin_nontemporal_load(Wp + 64);
    vfloat4 w2 = __builtin_nontemporal_load(Wp + 128);
    vfloat4 w3 = __builtin_nontemporal_load(Wp + 192);
    vfloat4 bbc = {0.f, 0.f, 0.f, 0.f};
    if (lane < 2) bbc = *bp;                         // bias, node n
    int idxn = (gw + NWAVES < N_NODES) ? np[NWAVES * K] : 0;  // nbr, node n+1
    float2 vc = *(const float2*)(values + (size_t)idxc * D + c2);  // gather, node n

    int n = gw;
    while (true) {
        const int  nn   = n + NWAVES;
        const bool more = (nn < N_NODES);

        // ---- Issue phase: next node's loads go in flight before compute ----
        float2  vn;
        vfloat4 x0, x1, x2, x3;
        vfloat4 bbn = {0.f, 0.f, 0.f, 0.f};
        int idxn2 = 0;
        if (more) {
            vn = *(const float2*)(values + (size_t)idxn * D + c2);
            x0 = __builtin_nontemporal_load(Wp + NWAVES * 256);
            x1 = __builtin_nontemporal_load(Wp + NWAVES * 256 + 64);
            x2 = __builtin_nontemporal_load(Wp + NWAVES * 256 + 128);
            x3 = __builtin_nontemporal_load(Wp + NWAVES * 256 + 192);
            if (lane < 2) bbn = bp[NWAVES * 2];
            if (nn + NWAVES < N_NODES) idxn2 = np[2 * NWAVES * K];
        }

        // ---- Compute phase: node n entirely from registers ----
        vfloat4 p = {0.f, 0.f, 0.f, 0.f};
        #pragma unroll
        for (int t = 0; t < 4; ++t) {
            const int   src = 16 * t + k4;
            const float ax  = __shfl(vc.x, src, 64);
            const float ay  = __shfl(vc.y, src, 64);
            const float gf  = hiC ? ay : ax;
            const vfloat4 w = (t == 0) ? w0 : (t == 1) ? w1 : (t == 2) ? w2 : w3;
            p.x = fmaf(gf, w.x, p.x);
            p.y = fmaf(gf, w.y, p.y);
            p.z = fmaf(gf, w.z, p.z);
            p.w = fmaf(gf, w.w, p.w);
        }

        #pragma unroll
        for (int m = 2; m <= 32; m <<= 1) {
            p.x += __shfl_xor(p.x, m, 64);
            p.y += __shfl_xor(p.y, m, 64);
            p.z += __shfl_xor(p.z, m, 64);
            p.w += __shfl_xor(p.w, m, 64);
        }

        if (lane < 2) {
            vfloat4 r;
            r.x = 1.f / (1.f + __expf(-(p.x + bbc.x)));
            r.y = 1.f / (1.f + __expf(-(p.y + bbc.y)));
            r.z = 1.f / (1.f + __expf(-(p.z + bbc.z)));
            r.w = 1.f / (1.f + __expf(-(p.w + bbc.w)));
            *op = r;
        }

        if (!more) break;

        // ---- Rotate pipeline registers, advance streams ----
        n    = nn;
        vc   = vn;
        idxn = idxn2;
        w0 = x0; w1 = x1; w2 = x2; w3 = x3;
        bbc = bbn;
        Wp += NWAVES * 256;
        np += NWAVES * K;
        bp += NWAVES * 2;
        op += NWAVES * 2;
    }
}

extern "C" void kernel_launch(void* const* d_in, const int* in_sizes, int n_in,
                              void* d_out, int out_size, void* d_ws, size_t ws_size,
                              hipStream_t stream) {
    const float* values = (const float*)d_in[0];  // [N, D]
    const int*   nbr    = (const int*)d_in[1];    // [N, K]
    const float* W      = (const float*)d_in[2];  // [N, K*D, D]
    const float* bias   = (const float*)d_in[3];  // [N, D]
    float*       out    = (float*)d_out;          // [N, D]

    node_linear_sigmoid_pipe<<<NBLOCKS, NTHREADS, 0, stream>>>(values, nbr, W, bias, out);
}